// Round 12
// baseline (264.819 us; speedup 1.0000x reference)
//
#include <hip/hip_runtime.h>

#define NT 128
#define SS 512
#define PW 132                         // padded per-wave partial-row stride (floats)

__device__ __forceinline__ float rdlane(float v, int lane) {
    return __int_as_float(__builtin_amdgcn_readlane(__float_as_int(v), lane));
}
__device__ __forceinline__ int fexp_of(float x) {
    return (int)((__float_as_uint(x) >> 23) & 0xFFu) - 127;
}
// barrier draining only LDS ops — global prefetches stay in flight
__device__ __forceinline__ void lds_barrier() {
    asm volatile("s_waitcnt lgkmcnt(0)\n\ts_barrier" ::: "memory");
}

__global__ void zero_out_kernel(float* out) { out[0] = 0.0f; }

__global__ __launch_bounds__(256, 1) void crf_fwd_kernel(
    const float* __restrict__ emissions,        // [B, S, NT] f32
    const int* __restrict__ tags,               // [B, S]
    const unsigned char* __restrict__ mask,     // [B, S]
    const float* __restrict__ trans,            // [NT, NT] f32
    float* __restrict__ out)                    // [1] f32
{
    const int b   = blockIdx.x;                 // one batch per block
    const int tid = threadIdx.x;                // 0..255
    const int l   = tid & 63;
    const int w   = tid >> 6;                   // wave 0..3: rows/states 32w..32w+31
    const int st  = (w << 5) + (l & 31);        // owned state (dup on lane halves)

    __shared__ float pbuf[2][4 * PW];           // [parity][wave*PW + col]
    __shared__ int   kbuf[4];
    __shared__ float redf[4];
    __shared__ float redg[4];

    const float*         emB = emissions + (size_t)b * SS * NT;
    const int*           tgB = tags + b * SS;
    const unsigned char* mkB = mask + b * SS;

    // ---- gold score fully hoisted off the recursion ----
    float gold = 0.0f;
    for (int t = tid; t < SS; t += 256) {
        int tg   = tgB[t];
        float mk = mkB[t] ? 1.0f : 0.0f;
        float a  = emB[(size_t)t * NT + tg];
        if (t > 0) a += trans[tgB[t - 1] * NT + tg];
        gold += a * mk;
    }

    // ---- expT: own 32 rows, cols l and l+64 -> 64 VGPRs ----
    float eTa[32], eTb[32];
    #pragma unroll
    for (int r = 0; r < 32; r++) {
        const float* row = trans + (size_t)((w << 5) + r) * NT;
        eTa[r] = __expf(row[l]);
        eTb[r] = __expf(row[l + 64]);
    }

    // ---- init: true alpha_j = p̂ * 2^S * e^{M0} (S global) ----
    float a0 = emB[st];
    {
        float v = a0;
        #pragma unroll
        for (int o = 16; o > 0; o >>= 1) v = fmaxf(v, __shfl_xor(v, o));
        if (l == 0) redf[w] = v;
    }
    __syncthreads();
    const float M0 = fmaxf(fmaxf(redf[0], redf[1]), fmaxf(redf[2], redf[3]));

    float p = __expf(a0 - M0);                  // p̂ for state st (duplicated)
    float S = 0.0f;
    int K = 0, kv_own = 0;

    // ---- emission pipeline: loads 4 deep, exp 2 steps off-chain ----
    float ex_o = __expf(emB[(size_t)1 * NT + st]);   // exp(e_1)
    float ex_e = __expf(emB[(size_t)2 * NT + st]);   // exp(e_2)
    float pd_o = emB[(size_t)3 * NT + st];
    float pd_e = emB[(size_t)4 * NT + st];

    // one recursion step: matvec -> exchange -> (off-chain work in latency
    // window) -> combine.  mode: 0=plain, 1=rescale+propose, 2=K-collect.
    auto step = [&](int t, int q, int mode, float& pd, float& ex) {
        // scalar-fmac matvec: 32 readlane + 64 v_fmac (SGPR src0, no movs)
        float aA0 = 0.f, aA1 = 0.f, aA2 = 0.f, aA3 = 0.f;
        float aB0 = 0.f, aB1 = 0.f, aB2 = 0.f, aB3 = 0.f;
        #pragma unroll
        for (int r = 0; r < 32; r += 4) {
            float q0 = rdlane(p, r + 0);
            float q1 = rdlane(p, r + 1);
            float q2 = rdlane(p, r + 2);
            float q3 = rdlane(p, r + 3);
            aA0 = fmaf(q0, eTa[r + 0], aA0);  aB0 = fmaf(q0, eTb[r + 0], aB0);
            aA1 = fmaf(q1, eTa[r + 1], aA1);  aB1 = fmaf(q1, eTb[r + 1], aB1);
            aA2 = fmaf(q2, eTa[r + 2], aA2);  aB2 = fmaf(q2, eTb[r + 2], aB2);
            aA3 = fmaf(q3, eTa[r + 3], aA3);  aB3 = fmaf(q3, eTb[r + 3], aB3);
        }
        float sA = (aA0 + aA1) + (aA2 + aA3);
        float sB = (aB0 + aB1) + (aB2 + aB3);

        pbuf[q][w * PW + l]      = sA;          // partial for col l
        pbuf[q][w * PW + l + 64] = sB;          // partial for col l+64
        if (mode == 1 && l == 0) kbuf[w] = kv_own;   // rides the barrier (next step reads)
        lds_barrier();                          // lgkm-only: vmcnt untouched

        // issue combine reads immediately
        float r0 = pbuf[q][0 * PW + st];
        float r1 = pbuf[q][1 * PW + st];
        float r2 = pbuf[q][2 * PW + st];
        float r3 = pbuf[q][3 * PW + st];

        // ---- off-chain work inside the LDS read-latency window ----
        float nr = pd;                          // raw e_{t+2}
        int tn = t + 4; if (tn > SS - 1) tn = SS - 1;
        pd = emB[(size_t)tn * NT + st];         // load e_{t+4} (stays in flight)
        float nex = __expf(nr);                 // exp for step t+2
        if (mode == 2) {                        // collect joint K (written last step)
            K = max(max(kbuf[0], kbuf[1]), max(kbuf[2], kbuf[3]));
        }

        // ---- combine + emission ----
        float sn = ((r0 + r1) + (r2 + r3)) * ex;
        ex = nex;

        if (mode == 1) {                        // group boundary: apply K, propose
            p = ldexpf(sn, -K);
            S += (float)K;
            int kv = fexp_of(p);
            #pragma unroll
            for (int o = 16; o > 0; o >>= 1) kv = max(kv, __shfl_xor(kv, o));
            kv_own = kv;
        } else {
            p = sn;
        }
    };

    // ---- forward recursion: groups of 4 steps; rescale at sub-step 0 ----
    #pragma unroll 1
    for (int t = 1; t < SS; t += 4) {
        step(t, 1, 1, pd_o, ex_o);                                // rescale+propose
        if (t + 1 < SS) step(t + 1, 0, 2, pd_e, ex_e);            // K collect
        if (t + 2 < SS) step(t + 2, 1, 0, pd_o, ex_o);            // plain
        if (t + 3 < SS) step(t + 3, 0, 0, pd_e, ex_e);            // plain
    }

    // ---- epilogue: partition = M0 + S*ln2 + log Σ p̂ ; reduce gold ----
    {
        float sw = (l < 32) ? p : 0.0f;         // states duplicated on lane halves
        float g  = gold;
        #pragma unroll
        for (int o = 32; o > 0; o >>= 1) {
            sw += __shfl_xor(sw, o);
            g  += __shfl_xor(g, o);
        }
        if (l == 0) { redf[w] = sw; redg[w] = g; }
    }
    __syncthreads();
    if (tid == 0) {
        float tot  = (redf[0] + redf[1]) + (redf[2] + redf[3]);
        float part = M0 + S * 0.69314718055994531f + __logf(tot);
        float gt   = (redg[0] + redg[1]) + (redg[2] + redg[3]);
        atomicAdd(out, part - gt);
    }
}

extern "C" void kernel_launch(void* const* d_in, const int* in_sizes, int n_in,
                              void* d_out, int out_size, void* d_ws, size_t ws_size,
                              hipStream_t stream) {
    const float*         emissions = (const float*)d_in[0];
    const int*           tags      = (const int*)d_in[1];
    const unsigned char* mask      = (const unsigned char*)d_in[2];
    const float*         trans     = (const float*)d_in[3];
    float*               out       = (float*)d_out;

    zero_out_kernel<<<1, 1, 0, stream>>>(out);
    crf_fwd_kernel<<<256, 256, 0, stream>>>(emissions, tags, mask, trans, out);
}